// Round 17
// baseline (286.555 us; speedup 1.0000x reference)
//
#include <hip/hip_runtime.h>
#include <stdint.h>

#define T_TOTAL 1096
#define WARMUP  365
#define NB      16384
#define T_OUT   (T_TOTAL - WARMUP)   // 731
#define U       8                    // steps per group
#define NG      (T_TOTAL / U)        // 137 real groups (+1 dummy)
#define RS      131072u              // input row stride bytes = NB*2*4
#define ORS     65536u               // output row stride bytes = NB*4

#define KEEP(x) asm volatile("" : "+v"(x))

typedef float f2 __attribute__((ext_vector_type(2)));
typedef float f4 __attribute__((ext_vector_type(4)));

typedef __attribute__((address_space(3))) char      lds_char;
typedef __attribute__((address_space(3))) uint32_t  lds_u32;
typedef const __attribute__((address_space(1))) uint32_t glb_u32;
typedef const __attribute__((address_space(3))) f4       lds_f4;

// Stores only READ registers -> safe as inline asm (R12 lesson: never use
// asm-dest LOADS at high register pressure). 32-bit voffset + SGPR base.
#define GSTORE2_Q(off, val) \
    asm volatile("global_store_dwordx2 %0, %1, %2" \
                 :: "v"(off), "v"(val), "s"(out))
#define GSTORE2_E(off, val) \
    asm volatile("global_store_dwordx2 %0, %1, %2" \
                 :: "v"(off), "v"(val), "s"(oute))

// ---- per-basin constants + state (token-pasted suffix S = 0 or 1) ----
#define DECL_BASIN(S)                                                          \
    float nkc##S, w1##S, k1##S, cxs##S, cxp##S, cxpk1##S, a0##S, na0##S,       \
          nb0##S, nc0##S, hm##S, a1##S, a2##S, b0##S, b1##S, c0p##S, c1p##S,   \
          d1##S, h##S, he1##S, kkA##S, kkB##S, ccA##S, dA##S, dB##S, gA##S,    \
          gB##S, nccAdA##S, nh1a1##S, nh2a2##S, nh3b1##S, nh4c1##S;            \
    float xf##S = 0.01f, xp##S = 0.01f, x2##S = 0.01f, xs##S = 0.01f,          \
          x3##S = 0.01f, x4##S = 0.01f, x5##S = 0.01f, qs##S = 0.01f;          \
    {   float pn[20];                                                          \
        _Pragma("unroll")                                                      \
        for (int i = 0; i < 20; ++i) pn[i] = (pp##S)[i];                       \
        const float kc  = 0.5f  + pn[0];                                       \
        const float w1_ = 1.0f  + pn[1]  * 99.0f;                              \
        const float w2_ = 1.0f  + pn[2]  * 99.0f;                              \
        const float k1_ = 0.01f + pn[3]  * 0.99f;                              \
        const float k2_ = 0.01f + pn[4]  * 0.99f;                              \
        const float a0_ = 0.01f + pn[5]  * 0.99f;                              \
        const float b0_ = 0.01f + pn[6]  * 0.99f;                              \
        const float c0_ = 0.01f + pn[7]  * 0.99f;                              \
        const float h1_ = pn[8]  * 90.0f;                                      \
        const float h2_ = pn[9]  * 100.0f;                                     \
        const float a1_ = 0.01f + pn[10] * 0.99f;                              \
        const float a2_ = 0.01f + pn[11] * 0.99f;                              \
        const float h3_ = pn[12] * 100.0f;                                     \
        const float b1_ = 0.01f + pn[13] * 0.99f;                              \
        const float h4_ = pn[14] * 100.0f;                                     \
        const float c1_ = 0.01f + pn[15] * 0.99f;                              \
        const float d1_ = 0.001f+ pn[16] * 0.999f;                             \
        const float e1_ = 0.01f + pn[17] * 0.99f;                              \
        const float e2_ = 0.01f + pn[18] * 0.99f;                              \
        const float h_  = pn[19] * 100.0f;                                     \
        const float dt  = 0.5f * (1.0f / 1000.0f);                             \
        const float invw = 1.0f / (w1_ + w2_);                                 \
        nkc##S = -kc;  w1##S = w1_;  k1##S = k1_;                              \
        cxs##S = k2_ * w1_ * invw;  cxp##S = k2_ * w2_ * invw;                 \
        cxpk1##S = cxp##S * k1_;                                               \
        a0##S = a0_;  na0##S = -a0_;  nb0##S = -b0_;  nc0##S = -c0_;           \
        a1##S = a1_;  a2##S = a2_;  b0##S = b0_;  b1##S = b1_;                 \
        c0p##S = c0_; c1p##S = c1_; d1##S = d1_;  h##S = h_;                   \
        hm##S = fminf(h1_, h2_);  he1##S = h_ * e1_;                           \
        kkA##S = 1.0f / (e1_ + e2_);  kkB##S = 1.0f / e1_;                     \
        ccA##S = e2_ * h_ * kkA##S;                                            \
        dA##S = 1.0f / (kkA##S + dt);  dB##S = 1.0f / (kkB##S + dt);           \
        gA##S = kkA##S - dt;  gB##S = kkB##S - dt;                             \
        nccAdA##S = -ccA##S * dA##S;                                           \
        nh1a1##S = -h1_ * a1_;  nh2a2##S = -h2_ * a2_;                         \
        nh3b1##S = -h3_ * b1_;  nh4c1##S = -h4_ * c1_;                         \
    }

#define KEEPC(S) do {                                                          \
    KEEP(nkc##S); KEEP(w1##S); KEEP(k1##S); KEEP(cxs##S); KEEP(cxp##S);        \
    KEEP(cxpk1##S); KEEP(a0##S); KEEP(na0##S); KEEP(nb0##S); KEEP(nc0##S);     \
    KEEP(hm##S); KEEP(a1##S); KEEP(a2##S); KEEP(b0##S); KEEP(b1##S);           \
    KEEP(c0p##S); KEEP(c1p##S); KEEP(d1##S); KEEP(h##S); KEEP(he1##S);         \
    KEEP(kkA##S); KEEP(kkB##S); KEEP(ccA##S); KEEP(dA##S); KEEP(dB##S);        \
    KEEP(gA##S); KEEP(gB##S); KEEP(nccAdA##S);                                 \
    KEEP(nh1a1##S); KEEP(nh2a2##S); KEEP(nh3b1##S); KEEP(nh4c1##S);            \
} while (0)

// One time step for basin S; output component C (x or y) of oq[r]/oe[r].
// Body math identical to R16 (absmax 32 verified).
#define STEP(S, C, pv, ev, DO_ET, r) do {                                      \
    const float pd = fmaf(nkc##S, (ev), (pv));                                 \
    const float pe = fmaxf(pd, 0.0f);                                          \
    const float pew1 = pe - w1##S;                                             \
    if (DO_ET) { const float ep = (pv) - pd;                                   \
                 oe[r].C = fminf(ep, (pv) + (xp##S + xf##S)); }                \
    const float u = fminf(xf##S + pd, xf##S);                                  \
    xf##S = fmaxf(u, 0.0f);                                                    \
    xp##S = fmaxf(xp##S + fminf(u, 0.0f), 0.0f);                               \
    const float minv = fminf(x2##S, w1##S - xp##S);                            \
    const float t1 = k1##S * minv;                                             \
    const float A2 = fmaf(cxs##S, xs##S, -(cxp##S * xp##S));                   \
    const float B2 = cxpk1##S * minv;                                          \
    const float t2 = fmaxf(A2 - B2, 0.0f);                                     \
    xp##S += t1;                                                               \
    x2##S = x2##S - t1;      /* clip exact-redundant */                        \
    xp##S += t2;                                                               \
    xs##S = xs##S - t2;      /* clip exact-redundant */                        \
    const float xppe = xp##S + pe;                                             \
    xf##S = xf##S + fmaxf(xp##S + pew1, 0.0f);                                 \
    xp##S = fminf(w1##S, xppe);                                                \
    const float f1v = a0##S * xf##S;                                           \
    const float s1v = fmaf(xf##S, a1##S, nh1a1##S);                            \
    const float s2v = fmaf(xf##S, a2##S, nh2a2##S);                            \
    const float rsv = fmaxf(s2v, 0.0f) + ((xf##S > hm##S) ? s1v : 0.0f);       \
    x2##S = x2##S + f1v;                                                       \
    xf##S = fmaxf(fmaf(na0##S, xf##S, xf##S) - rsv, 0.0f);                     \
    const float f2v = b0##S * x2##S;                                           \
    const float riv = fmaxf(fmaf(x2##S, b1##S, nh3b1##S), 0.0f);               \
    x3##S = x3##S + f2v;                                                       \
    x2##S = fmaxf(fmaf(nb0##S, x2##S, x2##S) - riv, 0.0f);                     \
    const float f3v = c0p##S * x3##S;                                          \
    const float rgv = fmaxf(fmaf(x3##S, c1p##S, nh4c1##S), 0.0f);              \
    x4##S = x4##S + f3v;                                                       \
    x3##S = fmaxf(fmaf(nc0##S, x3##S, x3##S) - rgv, 0.0f);                     \
    const float rgd = d1##S * x4##S;                                           \
    x4##S = x4##S - rgd;     /* clip redundant: RN(d1*x4)<=x4 */               \
    const bool  c5   = (x5##S >= h##S);                                        \
    const float kk0g = c5 ? gA##S : gB##S;                                     \
    const float cc0  = c5 ? ccA##S : 0.0f;                                     \
    const float ii   = (rsv + riv) + (rgv + rgd);                              \
    const float N1   = fmaf(kk0g, qs##S, ii + cc0);                            \
    const float q1B  = fmaxf(N1 * dB##S, 0.0f);                                \
    const float q1A  = fmaxf(fmaf(N1, dA##S, nccAdA##S), 0.0f);                \
    const bool  cb   = (q1B > he1##S);                                         \
    const float q1   = cb ? q1A : q1B;                                         \
    x5##S = cb ? fmaf(kkA##S, q1A, ccA##S) : (kkB##S * q1B);                   \
    qs##S = q1;                                                                \
    oq[r].C = q1;                                                              \
} while (0)

// 8 steps, two interleaved independent scalar chains per lane: chain 1's
// ops fill chain 0's ~4-cyc dependency gaps (one wave/SIMD has nothing else
// to fill them with).
#define BODY82(DO_ET)                                                          \
    _Pragma("unroll")                                                          \
    for (int r = 0; r < U; ++r) {                                              \
        STEP(0, x, s[r].x, s[r].y, DO_ET, r);                                  \
        STEP(1, y, s[r].z, s[r].w, DO_ET, r);                                  \
    }

#define WAIT() do {                                                            \
        asm volatile("s_waitcnt vmcnt(0)" ::: "memory");                       \
        __builtin_amdgcn_sched_barrier(0);                                     \
    } while (0)

#define PREFETCH(g, NXTOFF) do {                                               \
        const size_t t0n = ((g) + 1 < NG) ? (size_t)((g) + 1) * (8u * RS) : 0; \
        _Pragma("unroll")                                                      \
        for (int k = 0; k < U; ++k)                                            \
            __builtin_amdgcn_global_load_lds(                                  \
                (glb_u32*)(pe_base + t0n + (size_t)k * RS),                    \
                (lds_u32*)((lds_char*)smem + (NXTOFF) + k * 1024), 16, 0, 0);  \
    } while (0)

#define STAGE(CUROFF)                                                          \
    f4 s[U];                                                                   \
    _Pragma("unroll")                                                          \
    for (int r = 0; r < U; ++r)                                                \
        s[r] = *(lds_f4*)((lds_char*)smem + (CUROFF) + r * 1024 + lane16);     \
    _Pragma("unroll")                                                          \
    for (int r = 0; r < U; ++r) KEEP(s[r]);

#define GROUP_NS(g, CUROFF, NXTOFF, DO_ET) do {                                \
        WAIT(); PREFETCH(g, NXTOFF);                                           \
        asm volatile("" ::: "memory");                                         \
        STAGE(CUROFF) BODY82(DO_ET)                                            \
    } while (0)

// g=46 only: stores group 45's outputs, rows clamped to 0 (row-0 garbage is
// overwritten later in program order by the genuine t=365 values).
#define GROUP_CL(g, CUROFF, NXTOFF) do {                                       \
        WAIT(); PREFETCH(g, NXTOFF);                                           \
        {   const int tbP = ((g) - 1) * U - WARMUP;                            \
            _Pragma("unroll")                                                  \
            for (int r = 0; r < U; ++r) {                                      \
                int to = tbP + r; if (to < 0) to = 0;                          \
                const uint32_t v = vb8 + (uint32_t)to * ORS;                   \
                GSTORE2_Q(v, oq[r]); GSTORE2_E(v, oe[r]);                      \
            }                                                                  \
        }                                                                      \
        asm volatile("" ::: "memory");                                         \
        STAGE(CUROFF) BODY82(1)                                                \
    } while (0)

// hot path: running contiguous output address, one v_add per step.
#define GROUP_RV(g, CUROFF, NXTOFF) do {                                       \
        WAIT(); PREFETCH(g, NXTOFF);                                           \
        _Pragma("unroll")                                                      \
        for (int r = 0; r < U; ++r) {                                          \
            GSTORE2_Q(voq, oq[r]); GSTORE2_E(voq, oe[r]);                      \
            voq += ORS;                                                        \
        }                                                                      \
        asm volatile("" ::: "memory");                                         \
        STAGE(CUROFF) BODY82(1)                                                \
    } while (0)

// 8192 threads: each lane runs TWO independent scalar basin chains.
// waves_per_eu(1,1): full VGPR budget, no spills.
__global__ __attribute__((amdgpu_flat_work_group_size(64, 64)))
__attribute__((amdgpu_waves_per_eu(1, 1)))
void tank_kernel(
    const float* __restrict__ pe_in,   // [T, B, 2]
    const float* __restrict__ params,  // [B, 20]
    float* __restrict__ out)           // q [731,B] then et [731,B]
{
    const int lane = threadIdx.x;              // 0..63, one wave per block
    const int b    = blockIdx.x * 64 + lane;   // pair index: basins 2b, 2b+1

    __shared__ char smem[16384];               // 2 x 8KB double buffer

    const float* oute = out + (size_t)T_OUT * NB;   // et plane SGPR base

    const float* pp0 = params + (size_t)(2 * b) * 20;
    const float* pp1 = pp0 + 20;

    DECL_BASIN(0)
    DECL_BASIN(1)

    // staging addressing: wave covers 128 basins = 1024B per time row
    const char* pe_base = (const char*)pe_in + (size_t)blockIdx.x * 1024
                        + (size_t)lane * 16;       // per-lane global src
    const uint32_t lane16 = (uint32_t)lane * 16;   // LDS read offset
    const uint32_t vb8    = (uint32_t)b * 8u;      // output pair byte offset

    f2 oq[U], oe[U];

    // prologue: fill buffer 0 with group 0 (t=0..7)
#pragma unroll
    for (int k = 0; k < U; ++k)
        __builtin_amdgcn_global_load_lds(
            (glb_u32*)(pe_base + (size_t)k * RS),
            (lds_u32*)((lds_char*)smem + k * 1024), 16, 0, 0);

    // Phase 1: pure-warmup groups 0..43 as 22 pairs (no et, no stores).
#pragma clang loop unroll(disable)
    for (int gp = 0; gp < 22; ++gp) {
        KEEPC(0); KEEPC(1);
        const int g0i = 2 * gp;
        GROUP_NS(g0i,     0,    8192, 0);
        GROUP_NS(g0i + 1, 8192, 0,    0);
    }
    // group 44 (no et); group 45 (t=360..367: et computed, outputs buffered).
    KEEPC(0); KEEPC(1);
    GROUP_NS(44, 0,    8192, 0);
    GROUP_NS(45, 8192, 0,    1);

    // group 46: stores group 45's outputs with row clamp (outside hot loop).
    KEEPC(0); KEEPC(1);
    GROUP_CL(46, 0, 8192);

    // running output address from group 47 (stores rows 3..10, contiguous on).
    uint32_t voq = vb8 + 3u * ORS;
    GROUP_RV(47, 8192, 0);

    // Phase 2: groups 48..137 as 45 pairs. Group 137 is a dummy (computes
    // discarded garbage from in-bounds t=0 data; stores group 136's outputs).
#pragma clang loop unroll(disable)
    for (int gp = 0; gp < 45; ++gp) {
        KEEPC(0); KEEPC(1);
        const int g0i = 48 + 2 * gp;
        GROUP_RV(g0i,     0,    8192);
        GROUP_RV(g0i + 1, 8192, 0);
    }
}

extern "C" void kernel_launch(void* const* d_in, const int* in_sizes, int n_in,
                              void* d_out, int out_size, void* d_ws, size_t ws_size,
                              hipStream_t stream) {
    const float* pe_in  = (const float*)d_in[0];   // [1096, 16384, 2] f32
    const float* params = (const float*)d_in[1];   // [16384, 20] f32
    float* out = (float*)d_out;                    // 2 * 731 * 16384 f32

    tank_kernel<<<NB / 128, 64, 0, stream>>>(pe_in, params, out);
}

// Round 18
// 151.044 us; speedup vs baseline: 1.8972x; 1.8972x over previous
//
#include <hip/hip_runtime.h>
#include <stdint.h>

#define T_TOTAL 1096
#define WARMUP  365
#define NB      16384
#define T_OUT   (T_TOTAL - WARMUP)   // 731
#define U       8                    // steps per group
#define NG      (T_TOTAL / U)        // 137 real groups (+1 dummy)
#define RS      131072u              // input row stride bytes = NB*2*4
#define ORS     65536u               // output row stride bytes = NB*4

// Pin a value into a VGPR at this program point (volatile asm chain).
#define KEEP(x) asm volatile("" : "+v"(x))

typedef float f2 __attribute__((ext_vector_type(2)));

// Volatile register-destination global load (saddr form). R12 lesson: safe
// only at low register pressure. Holds at ~132 VGPR (R11/R14/R15/R16 passing);
// R17 showed the dual-chain variant exceeds the safe pressure -> reverted.
#define GLOAD(dst, off) \
    asm volatile("global_load_dwordx2 %0, %1, %2" \
                 : "=v"(dst) : "v"(off), "s"(pe_in))

// saddr-form stores: 32-bit voffset + uniform SGPR base (no VCC carry adds).
// Separate bases for the q plane and the et plane (kills +EOFF adds).
#define GSTORE_Q(off, val) \
    asm volatile("global_store_dword %0, %1, %2" \
                 :: "v"(off), "v"(val), "s"(out))
#define GSTORE_E(off, val) \
    asm volatile("global_store_dword %0, %1, %2" \
                 :: "v"(off), "v"(val), "s"(oute))

// ---- compute body for one group of U=8 steps (shared by all variants) ----
#define BODY8(CUR, DO_ET)                                                      \
        _Pragma("unroll")                                                      \
        for (int r = 0; r < U; ++r) {                                          \
            const float p  = CUR[r].x;   /* inputs >=0: clip is identity */    \
            const float e  = CUR[r].y;                                         \
            const float pd = fmaf(nkc, e, p);       /* p - kc*e */             \
            const float pe = fmaxf(pd, 0.0f);                                  \
            const float pew1 = pe - w1;             /* off-chain hoist */      \
            if (DO_ET) { const float ep = p - pd;                              \
                         oe[r] = fminf(ep, p + (xp + xf)); }                   \
            /* u-trick: xf' = max(u,0), xp' = max(xp+min(u,0),0) */            \
            const float u  = fminf(xf + pd, xf);                               \
            xf = fmaxf(u, 0.0f);                                               \
            xp = fmaxf(xp + fminf(u, 0.0f), 0.0f);                             \
            const float minv = fminf(x2, w1 - xp);                             \
            const float t1 = k1 * minv;                                        \
            /* t2 decoupled from xp2: cxp*(xp1+t1) distributed */              \
            const float A2 = fmaf(cxs, xs, -(cxp * xp));                       \
            const float B2 = cxpk1 * minv;                                     \
            const float t2 = fmaxf(A2 - B2, 0.0f);                             \
            xp += t1;                                                          \
            x2 = x2 - t1;    /* clip exact-redundant: t1<=minv<=x2 (RN) */     \
            xp += t2;                                                          \
            xs = xs - t2;    /* clip exact-redundant: t2<=RN(cxs*xs)<=xs */    \
            const float xppe = xp + pe;                                        \
            xf = xf + fmaxf(xp + pew1, 0.0f);   /* xf1 + max(xppe-w1,0) */     \
            xp = fminf(w1, xppe);                                              \
            const float f1v = a0 * xf;                                         \
            const float s1v = fmaf(xf, a1, nh1a1);                             \
            const float s2v = fmaf(xf, a2, nh2a2);                             \
            /* a2>0: h2-select == fmax(s2v,0) */                               \
            const float rsv = fmaxf(s2v, 0.0f) + ((xf > hm) ? s1v : 0.0f);     \
            x2 = x2 + f1v;                                                     \
            xf = fmaxf(fmaf(na0, xf, xf) - rsv, 0.0f);                         \
            const float f2v = b0 * x2;                                         \
            const float riv = fmaxf(fmaf(x2, b1, nh3b1), 0.0f);                \
            x3 = x3 + f2v;                       /* uses x2 pre-overwrite */   \
            x2 = fmaxf(fmaf(nb0, x2, x2) - riv, 0.0f);                         \
            const float f3v = c0p * x3;                                        \
            const float rgv = fmaxf(fmaf(x3, c1p, nh4c1), 0.0f);               \
            x4 = x4 + f3v;                       /* uses x3 pre-overwrite */   \
            x3 = fmaxf(fmaf(nc0, x3, x3) - rgv, 0.0f);                         \
            const float rgd = d1 * x4;                                         \
            x4 = x4 - rgd;   /* clip redundant: RN(d1*x4)<=x4 for d1<=1 */     \
            const bool  c5   = (x5 >= h);                                      \
            const float kk0g = c5 ? gA : gB;                                   \
            const float cc0  = c5 ? ccA : 0.0f;                                \
            const float ii   = (rsv + riv) + (rgv + rgd);                      \
            const float N1   = fmaf(kk0g, qs, ii + cc0);                       \
            const float q1B  = fmaxf(N1 * dB, 0.0f);                           \
            const float q1A  = fmaxf(fmaf(N1, dA, nccAdA), 0.0f);              \
            const bool  cb   = (q1B > he1);                                    \
            const float q1   = cb ? q1A : q1B;                                 \
            x5 = cb ? fmaf(kkA, q1A, ccA) : (kkB * q1B);                       \
            qs = q1;                                                           \
            oq[r] = q1;                                                        \
        }

#define PREFETCH(g, NXT) do {                                                  \
        const uint32_t t0n = ((g) + 1 < NG) ? (uint32_t)((g) + 1) * (8u * RS) : 0u; \
        _Pragma("unroll")                                                      \
        for (int k = 0; k < U; ++k) {                                          \
            uint32_t o = boff + t0n + (uint32_t)k * RS;                        \
            GLOAD(NXT[k], o);                                                  \
        }                                                                      \
    } while (0)

#define WAIT() do {                                                            \
        asm volatile("s_waitcnt vmcnt(0)" ::: "memory");                       \
        __builtin_amdgcn_sched_barrier(0);                                     \
    } while (0)

// no-store group (warmup)
#define GROUP_NS(g, CUR, NXT, DO_ET) do {                                      \
        WAIT(); PREFETCH(g, NXT); BODY8(CUR, DO_ET)                            \
    } while (0)

// clamp-store group (g=46 only: stores group 45's outputs, rows clamp to 0;
// row 0 garbage is overwritten later in program order by the genuine t=365)
#define GROUP_CL(g, CUR, NXT) do {                                             \
        WAIT(); PREFETCH(g, NXT);                                              \
        {                                                                      \
            const int tbP = ((g) - 1) * U - WARMUP;                            \
            _Pragma("unroll")                                                  \
            for (int r = 0; r < U; ++r) {                                      \
                int to = tbP + r; if (to < 0) to = 0;                          \
                const uint32_t v = vb4 + (uint32_t)to * ORS;                   \
                GSTORE_Q(v, oq[r]); GSTORE_E(v, oe[r]);                        \
            }                                                                  \
        }                                                                      \
        BODY8(CUR, 1)                                                          \
    } while (0)

// running-voq store group (phase-2 hot path): output rows are globally
// contiguous across groups -> one v_add per step for addressing.
#define GROUP_RV(g, CUR, NXT) do {                                             \
        WAIT(); PREFETCH(g, NXT);                                              \
        _Pragma("unroll")                                                      \
        for (int r = 0; r < U; ++r) {                                          \
            GSTORE_Q(voq, oq[r]); GSTORE_E(voq, oe[r]);                        \
            voq += ORS;                                                        \
        }                                                                      \
        BODY8(CUR, 1)                                                          \
    } while (0)

#define KEEP_CONSTS() do {                                                     \
        KEEP(nkc); KEEP(w1);  KEEP(k1);  KEEP(cxs); KEEP(cxp); KEEP(cxpk1);    \
        KEEP(a0);  KEEP(na0); KEEP(nb0); KEEP(nc0); KEEP(hm);                  \
        KEEP(a1);  KEEP(a2);  KEEP(b0);  KEEP(b1);  KEEP(c0p); KEEP(c1p);      \
        KEEP(d1);  KEEP(h);   KEEP(he1);                                       \
        KEEP(kkA); KEEP(kkB); KEEP(ccA); KEEP(dA);  KEEP(dB);                  \
        KEEP(gA);  KEEP(gB);  KEEP(nccAdA);                                    \
        KEEP(nh1a1); KEEP(nh2a2); KEEP(nh3b1); KEEP(nh4c1);                    \
    } while (0)

// waves_per_eu(1,1): occupancy is structurally 1 wave/EU (256 waves on 1024
// SIMDs); cap removes occupancy pressure -> full VGPR budget, no spills
// (verified R10: VGPR_Count 64 -> 132).
__global__ __attribute__((amdgpu_flat_work_group_size(64, 64)))
__attribute__((amdgpu_waves_per_eu(1, 1)))
void tank_kernel(
    const float* __restrict__ pe_in,   // [T, B, 2]
    const float* __restrict__ params,  // [B, 20]
    float* __restrict__ out)           // q [731,B] then et [731,B]
{
    const int lane = threadIdx.x;          // 0..63, one wave per block
    const int b    = blockIdx.x * 64 + lane;

    const float* oute = out + (size_t)T_OUT * NB;   // et plane SGPR base

    float pn[20];
#pragma unroll
    for (int i = 0; i < 20; ++i) pn[i] = params[b * 20 + i];

    float kc  = 0.5f  + pn[0]  * 1.0f;
    float w1  = 1.0f  + pn[1]  * 99.0f;
    float w2  = 1.0f  + pn[2]  * 99.0f;
    float k1  = 0.01f + pn[3]  * 0.99f;
    float k2  = 0.01f + pn[4]  * 0.99f;
    float a0  = 0.01f + pn[5]  * 0.99f;
    float b0  = 0.01f + pn[6]  * 0.99f;
    float c0p = 0.01f + pn[7]  * 0.99f;
    float h1  = pn[8]  * 90.0f;
    float h2  = pn[9]  * 100.0f;
    float a1  = 0.01f + pn[10] * 0.99f;
    float a2  = 0.01f + pn[11] * 0.99f;
    float h3  = pn[12] * 100.0f;
    float b1  = 0.01f + pn[13] * 0.99f;
    float h4  = pn[14] * 100.0f;
    float c1p = 0.01f + pn[15] * 0.99f;
    float d1  = 0.001f+ pn[16] * 0.999f;
    float e1  = 0.01f + pn[17] * 0.99f;
    float e2  = 0.01f + pn[18] * 0.99f;
    float h   = pn[19] * 100.0f;

    const float dt = 0.5f * (1.0f / 1000.0f);
    float invw = 1.0f / (w1 + w2);
    float cxs  = k2 * w1 * invw;
    float cxp  = k2 * w2 * invw;
    float kkA  = 1.0f / (e1 + e2);
    float kkB  = 1.0f / e1;
    float ccA  = e2 * h * kkA;
    float dA   = 1.0f / (kkA + dt);
    float dB   = 1.0f / (kkB + dt);
    float gA   = kkA - dt;
    float gB   = kkB - dt;
    float nh1a1 = -h1 * a1;
    float nh2a2 = -h2 * a2;
    float nh3b1 = -h3 * b1;
    float nh4c1 = -h4 * c1p;
    float hm    = fminf(h1, h2);
    float he1   = h * e1;
    float nccAdA = -ccA * dA;
    float nkc   = -kc;
    float cxpk1 = cxp * k1;
    float na0   = -a0;
    float nb0   = -b0;
    float nc0   = -c0p;

    float xf = 0.01f, xp = 0.01f, x2 = 0.01f, xs = 0.01f;
    float x3 = 0.01f, x4 = 0.01f, x5 = 0.01f, qs = 0.01f;

    const uint32_t boff = (uint32_t)b * 8u;   // input: lane byte off in a row
    const uint32_t vb4  = (uint32_t)b * 4u;   // output: lane byte off in a row

    f2 bufA[U], bufB[U];
    float oq[U], oe[U];

    // prologue: issue loads for group 0 into set A
#pragma unroll
    for (int k = 0; k < U; ++k) {
        uint32_t o = boff + (uint32_t)k * RS;
        GLOAD(bufA[k], o);
    }

    // Phase 1: pure-warmup groups 0..43 as 22 pairs (no et, no stores).
#pragma clang loop unroll(disable)
    for (int gp = 0; gp < 22; ++gp) {
        KEEP_CONSTS();
        const int g0i = 2 * gp;
        GROUP_NS(g0i,     bufA, bufB, 0);
        GROUP_NS(g0i + 1, bufB, bufA, 0);
    }
    // group 44 (no et); group 45 (t=360..367: et computed, outputs buffered).
    KEEP_CONSTS();
    GROUP_NS(44, bufA, bufB, 0);
    GROUP_NS(45, bufB, bufA, 1);

    // group 46: stores group 45's outputs with row clamp (outside hot loop).
    KEEP_CONSTS();
    GROUP_CL(46, bufA, bufB);

    // running output address: group 47 stores group 46's outputs, rows 3..10,
    // and rows are globally contiguous from here on.
    uint32_t voq = vb4 + 3u * ORS;
    GROUP_RV(47, bufB, bufA);

    // Phase 2: groups 48..137 as 45 pairs. Group 137 is a dummy: computes
    // discarded garbage from in-bounds t=0 data; its store slot writes group
    // 136's real outputs (rows 723..730); its prefetch is never waited on.
#pragma clang loop unroll(disable)
    for (int gp = 0; gp < 45; ++gp) {
        KEEP_CONSTS();
        const int g0i = 48 + 2 * gp;
        GROUP_RV(g0i,     bufA, bufB);
        GROUP_RV(g0i + 1, bufB, bufA);
    }
}

extern "C" void kernel_launch(void* const* d_in, const int* in_sizes, int n_in,
                              void* d_out, int out_size, void* d_ws, size_t ws_size,
                              hipStream_t stream) {
    const float* pe_in  = (const float*)d_in[0];   // [1096, 16384, 2] f32
    const float* params = (const float*)d_in[1];   // [16384, 20] f32
    float* out = (float*)d_out;                    // 2 * 731 * 16384 f32

    tank_kernel<<<NB / 64, 64, 0, stream>>>(pe_in, params, out);
}